// Round 8
// baseline (1806.087 us; speedup 1.0000x reference)
//
#include <hip/hip_runtime.h>
#include <hip/hip_bf16.h>
#include <math.h>

typedef __hip_bfloat16 bf16;
typedef __attribute__((ext_vector_type(8))) short short8;
typedef __attribute__((ext_vector_type(4))) float f32x4;

#define S_LEN 1024
#define BATCH 4
#define M_ROWS 4096
#define DMODEL 1024
#define DFF 4096
#define NHEAD 8
#define DHEAD 128
#define WIN 100
#define LFWD 20

#define SCHED0 __builtin_amdgcn_sched_barrier(0)

__device__ __forceinline__ void gl_lds16(const void* g, void* l) {
    __builtin_amdgcn_global_load_lds(
        (const __attribute__((address_space(1))) void*)g,
        (__attribute__((address_space(3))) void*)l, 16, 0, 0);
}

__device__ __forceinline__ float bf2f(unsigned short u) {
    return __uint_as_float(((unsigned)u) << 16);
}

// XCD-aware bijective swizzle (nb is always a multiple of 8 here):
__device__ __forceinline__ int xcd_swz(int flat, int nb) {
    return (flat & 7) * (nb >> 3) + (flat >> 3);
}

// ---------------- MFMA GEMM (no split): C = act(A @ Bt^T + bias) ----------------
// depth-2 pipeline (32 KB LDS -> up to 5 blocks/CU), counted vmcnt.
template<typename TC>
__global__ __launch_bounds__(256)
void mfma_gemm(const bf16* __restrict__ A, const bf16* __restrict__ Bt,
               const float* __restrict__ bias, TC* __restrict__ C,
               int M, int N, int K, int act)
{
    __shared__ bf16 As[2][128 * 32];
    __shared__ bf16 Bs[2][128 * 32];
    const int gx = gridDim.x;
    const int nb = gx * gridDim.y;
    const int swz = xcd_swz(blockIdx.x + gx * blockIdx.y, nb);
    const int bn = (swz % gx) * 128;
    const int bm = (swz / gx) * 128;
    const int tid = threadIdx.x;
    const int w = tid >> 6, lane = tid & 63;
    const int wm = (w & 1) * 64, wn = (w >> 1) * 64;

    const int srow = w * 32 + (lane >> 2);
    const int selem = (lane & 3) * 8;
    const bf16* ga0 = A + (size_t)(bm + srow) * K + selem;
    const bf16* ga1 = ga0 + (size_t)16 * K;
    const bf16* gb0 = Bt + (size_t)(bn + srow) * K + selem;
    const bf16* gb1 = gb0 + (size_t)16 * K;
    const int l0 = (w * 32) * 32;
    const int l1 = (w * 32 + 16) * 32;

    f32x4 acc[4][4] = {};
    const int koff = (lane >> 4) * 8;
    const int fr = lane & 15;

    auto STAGE = [&](int t, int buf) {
        gl_lds16(ga0 + t * 32, As[buf] + l0);
        gl_lds16(ga1 + t * 32, As[buf] + l1);
        gl_lds16(gb0 + t * 32, Bs[buf] + l0);
        gl_lds16(gb1 + t * 32, Bs[buf] + l1);
    };

    const int nk = K >> 5;
    STAGE(0, 0);
    if (nk > 1) STAGE(1, 1);

    for (int t = 0; t < nk; ++t) {
        if (t < nk - 1) asm volatile("s_waitcnt vmcnt(4)" ::: "memory");
        else            asm volatile("s_waitcnt vmcnt(0)" ::: "memory");
        SCHED0;
        __builtin_amdgcn_s_barrier();
        SCHED0;
        const bf16* Ac = As[t & 1];
        const bf16* Bc = Bs[t & 1];
        short8 af[4], bfr[4];
#pragma unroll
        for (int i = 0; i < 4; ++i)
            af[i] = *(const short8*)(Ac + (wm + i * 16 + fr) * 32 + koff);
#pragma unroll
        for (int j = 0; j < 4; ++j)
            bfr[j] = *(const short8*)(Bc + (wn + j * 16 + fr) * 32 + koff);
#pragma unroll
        for (int i = 0; i < 4; ++i)
#pragma unroll
            for (int j = 0; j < 4; ++j)
                acc[i][j] = __builtin_amdgcn_mfma_f32_16x16x32_bf16(
                    af[i], bfr[j], acc[i][j], 0, 0, 0);
        asm volatile("s_waitcnt lgkmcnt(0)" ::: "memory");
        SCHED0;
        __builtin_amdgcn_s_barrier();
        SCHED0;
        if (t + 2 < nk) STAGE(t + 2, t & 1);
    }

    const int cq = lane >> 4, cn = lane & 15;
#pragma unroll
    for (int i = 0; i < 4; ++i) {
#pragma unroll
        for (int r = 0; r < 4; ++r) {
            int row = bm + wm + i * 16 + cq * 4 + r;
#pragma unroll
            for (int j = 0; j < 4; ++j) {
                int col = bn + wn + j * 16 + cn;
                float v = acc[i][j][r] + bias[col];
                if (act) v = v / (1.0f + __expf(-v));   // silu
                C[(size_t)row * N + col] = (TC)v;
            }
        }
    }
}

// ---- MFMA GEMM, K split over gridDim.z, atomic accumulate: C += A@Bt^T (+bias) ----
// C must hold the residual (or zeros) before launch. z==0 adds bias.
__global__ __launch_bounds__(256)
void mfma_gemm_at(const bf16* __restrict__ A, const bf16* __restrict__ Bt,
                  const float* __restrict__ bias, float* __restrict__ C,
                  int M, int N, int K)
{
    __shared__ bf16 As[2][128 * 32];
    __shared__ bf16 Bs[2][128 * 32];
    const int gx = gridDim.x, gy = gridDim.y, gz = gridDim.z;
    const int nb = gx * gy * gz;
    const int swz = xcd_swz(blockIdx.x + gx * (blockIdx.y + gy * blockIdx.z), nb);
    const int bn = (swz % gx) * 128;
    const int bm = ((swz / gx) % gy) * 128;
    const int z  = swz / (gx * gy);
    const int kz = K / gz;
    const int kstart = z * kz;
    const int tid = threadIdx.x;
    const int w = tid >> 6, lane = tid & 63;
    const int wm = (w & 1) * 64, wn = (w >> 1) * 64;

    const int srow = w * 32 + (lane >> 2);
    const int selem = (lane & 3) * 8;
    const bf16* ga0 = A + (size_t)(bm + srow) * K + kstart + selem;
    const bf16* ga1 = ga0 + (size_t)16 * K;
    const bf16* gb0 = Bt + (size_t)(bn + srow) * K + kstart + selem;
    const bf16* gb1 = gb0 + (size_t)16 * K;
    const int l0 = (w * 32) * 32;
    const int l1 = (w * 32 + 16) * 32;

    f32x4 acc[4][4] = {};
    const int koff = (lane >> 4) * 8;
    const int fr = lane & 15;

    auto STAGE = [&](int t, int buf) {
        gl_lds16(ga0 + t * 32, As[buf] + l0);
        gl_lds16(ga1 + t * 32, As[buf] + l1);
        gl_lds16(gb0 + t * 32, Bs[buf] + l0);
        gl_lds16(gb1 + t * 32, Bs[buf] + l1);
    };

    const int nk = kz >> 5;
    STAGE(0, 0);
    if (nk > 1) STAGE(1, 1);

    for (int t = 0; t < nk; ++t) {
        if (t < nk - 1) asm volatile("s_waitcnt vmcnt(4)" ::: "memory");
        else            asm volatile("s_waitcnt vmcnt(0)" ::: "memory");
        SCHED0;
        __builtin_amdgcn_s_barrier();
        SCHED0;
        const bf16* Ac = As[t & 1];
        const bf16* Bc = Bs[t & 1];
        short8 af[4], bfr[4];
#pragma unroll
        for (int i = 0; i < 4; ++i)
            af[i] = *(const short8*)(Ac + (wm + i * 16 + fr) * 32 + koff);
#pragma unroll
        for (int j = 0; j < 4; ++j)
            bfr[j] = *(const short8*)(Bc + (wn + j * 16 + fr) * 32 + koff);
#pragma unroll
        for (int i = 0; i < 4; ++i)
#pragma unroll
            for (int j = 0; j < 4; ++j)
                acc[i][j] = __builtin_amdgcn_mfma_f32_16x16x32_bf16(
                    af[i], bfr[j], acc[i][j], 0, 0, 0);
        asm volatile("s_waitcnt lgkmcnt(0)" ::: "memory");
        SCHED0;
        __builtin_amdgcn_s_barrier();
        SCHED0;
        if (t + 2 < nk) STAGE(t + 2, t & 1);
    }

    const int cq = lane >> 4, cn = lane & 15;
#pragma unroll
    for (int i = 0; i < 4; ++i) {
#pragma unroll
        for (int r = 0; r < 4; ++r) {
            int row = bm + wm + i * 16 + cq * 4 + r;
#pragma unroll
            for (int j = 0; j < 4; ++j) {
                int col = bn + wn + j * 16 + cn;
                float v = acc[i][j][r];
                if (z == 0) v += bias[col];
                atomicAdd(&C[(size_t)row * N + col], v);
            }
        }
    }
}

// -------- transpose+cast: W (K x N fp32, row stride ld) -> Wt (N x K bf16) --------
__global__ void transpose_kernel(const float* __restrict__ W, bf16* __restrict__ Wt,
                                 int K, int N, int ld)
{
    __shared__ float t[32][33];
    const int n0 = blockIdx.x * 32, k0 = blockIdx.y * 32;
    const int tx = threadIdx.x & 31, ty = threadIdx.x >> 5;
#pragma unroll
    for (int i = 0; i < 32; i += 8)
        t[ty + i][tx] = W[(size_t)(k0 + ty + i) * ld + n0 + tx];
    __syncthreads();
#pragma unroll
    for (int i = 0; i < 32; i += 8)
        Wt[(size_t)(n0 + ty + i) * K + k0 + tx] = (bf16)t[tx][ty + i];
}

// -------- v (qkv col 2048+) -> vt[b][h][d][s] bf16 --------
__global__ void vtrans_kernel(const bf16* __restrict__ qkv, bf16* __restrict__ vt)
{
    __shared__ bf16 t[32][33];
    const int bh = blockIdx.z;
    const int s0 = blockIdx.x * 32, d0 = blockIdx.y * 32;
    const int b = bh >> 3, h = bh & 7;
    const int tx = threadIdx.x & 31, ty = threadIdx.x >> 5;
#pragma unroll
    for (int i = 0; i < 32; i += 8)
        t[ty + i][tx] = qkv[(size_t)(b * S_LEN + s0 + ty + i) * 3072 + 2048
                            + h * DHEAD + d0 + tx];
    __syncthreads();
#pragma unroll
    for (int i = 0; i < 32; i += 8)
        vt[(size_t)(bh * DHEAD + d0 + ty + i) * 1024 + s0 + tx] = t[tx][ty + i];
}

// ---------------- fp32 -> bf16 convert ----------------
__global__ void cvt_kernel(const float* __restrict__ s, bf16* __restrict__ d)
{
    size_t i = ((size_t)blockIdx.x * 256 + threadIdx.x) * 4;
    float4 v = *(const float4*)(s + i);
    d[i] = (bf16)v.x; d[i + 1] = (bf16)v.y; d[i + 2] = (bf16)v.z; d[i + 3] = (bf16)v.w;
}

// ---------------- zero fp32 buffer (float4) ----------------
__global__ void zero_kernel(float* __restrict__ p)
{
    size_t i = ((size_t)blockIdx.x * 256 + threadIdx.x) * 4;
    *(float4*)(p + i) = make_float4(0.f, 0.f, 0.f, 0.f);
}

// ---------------- concat 3 bias vectors of 1024 fp32 ----------------
__global__ void concat3_kernel(const float* __restrict__ a, const float* __restrict__ b,
                               const float* __restrict__ c, float* __restrict__ o)
{
    int i = blockIdx.x * 256 + threadIdx.x;
    o[i] = (i < 1024) ? a[i] : (i < 2048 ? b[i - 1024] : c[i - 2048]);
}

// ---------------- zero padded rows of h ----------------
__global__ void pad_zero_kernel(float* __restrict__ h, const int* __restrict__ xlen)
{
    int row = blockIdx.x;
    int b = row >> 10, s = row & 1023;
    int len = xlen[b] >> 2;
    if (s < len) return;
    size_t off = (size_t)row * DMODEL;
#pragma unroll
    for (int t = 0; t < 4; ++t) h[off + threadIdx.x + 256 * t] = 0.0f;
}

// ---------------- LayerNorm (row of 1024) ----------------
template<typename TO>
__global__ void ln_kernel(const float* __restrict__ x,
                          const float* __restrict__ sc, const float* __restrict__ bi,
                          TO* __restrict__ y)
{
    int row = blockIdx.x;
    const float* xr = x + (size_t)row * DMODEL;
    float vals[4];
    float lsum = 0.0f, lsq = 0.0f;
#pragma unroll
    for (int t = 0; t < 4; ++t) {
        int d = threadIdx.x + 256 * t;
        float v = xr[d];
        vals[t] = v; lsum += v; lsq += v * v;
    }
    for (int o = 32; o > 0; o >>= 1) {
        lsum += __shfl_down(lsum, o, 64);
        lsq  += __shfl_down(lsq,  o, 64);
    }
    __shared__ float s1[4], s2[4];
    int wv = threadIdx.x >> 6, ln = threadIdx.x & 63;
    if (ln == 0) { s1[wv] = lsum; s2[wv] = lsq; }
    __syncthreads();
    if (threadIdx.x == 0) {
        float a = s1[0] + s1[1] + s1[2] + s1[3];
        float b = s2[0] + s2[1] + s2[2] + s2[3];
        float mu = a * (1.0f / DMODEL);
        float var = b * (1.0f / DMODEL) - mu * mu;
        s1[0] = mu;
        s2[0] = rsqrtf(fmaxf(var, 0.0f) + 1e-5f);
    }
    __syncthreads();
    float mu = s1[0], inv = s2[0];
#pragma unroll
    for (int t = 0; t < 4; ++t) {
        int d = threadIdx.x + 256 * t;
        y[(size_t)row * DMODEL + d] = (TO)((vals[t] - mu) * inv * sc[d] + bi[d]);
    }
}

// ---------------- RoPE (in-place, bf16, strided) ----------------
__global__ void rope_kernel(bf16* __restrict__ q, bf16* __restrict__ k, int stride)
{
    size_t idx = (size_t)blockIdx.x * 256 + threadIdx.x;
    int d = idx & 63;
    size_t rest = idx >> 6;
    int hh = rest & 7;
    int s = (rest >> 3) & 1023;
    size_t base = (rest >> 3) * stride + (size_t)hh * DHEAD;
    float inv = exp2f((float)d * -0.20762050593045235f);
    float ang = (float)s * inv;
    float c, si;
    __sincosf(ang, &si, &c);
    {
        float x1 = (float)q[base + d], x2 = (float)q[base + 64 + d];
        q[base + d]      = (bf16)(x1 * c - x2 * si);
        q[base + 64 + d] = (bf16)(x1 * si + x2 * c);
    }
    {
        float x1 = (float)k[base + d], x2 = (float)k[base + 64 + d];
        k[base + d]      = (bf16)(x1 * c - x2 * si);
        k[base + 64 + d] = (bf16)(x1 * si + x2 * c);
    }
}

// ------- mean of v over s, two-stage -------
__global__ void vmean_part(const bf16* __restrict__ v, float* __restrict__ part,
                           int stride)
{
    int g = blockIdx.x;
    int chunk = g & 31;
    int bh = g >> 5;
    int b = bh >> 3, hh = bh & 7;
    int d = threadIdx.x;
    const bf16* base = v + ((size_t)(b * S_LEN + chunk * 32)) * stride
                         + hh * DHEAD + d;
    float acc = 0.0f;
#pragma unroll 4
    for (int s = 0; s < 32; ++s)
        acc += (float)base[(size_t)s * stride];
    part[((size_t)bh * 32 + chunk) * DHEAD + d] = acc;
}

__global__ void vmean_fin(const float* __restrict__ part, float* __restrict__ vmean)
{
    int bh = blockIdx.x;
    int d = threadIdx.x;
    float acc = 0.0f;
#pragma unroll
    for (int c = 0; c < 32; ++c)
        acc += part[((size_t)bh * 32 + c) * DHEAD + d];
    vmean[(size_t)bh * DHEAD + d] = acc * (1.0f / S_LEN);
}

// ============== MFMA windowed attention ==============
__global__ __launch_bounds__(128)
void attn_mfma(const bf16* __restrict__ qkv, const bf16* __restrict__ vt_g,
               const float* __restrict__ vmean, const int* __restrict__ xlen,
               bf16* __restrict__ ctx)
{
    __shared__ bf16 KV[2][64 * 128];     // 2 x 16 KB
    __shared__ bf16 P[2][16 * 192];      // per-wave P, 12 KB

    const int qt = blockIdx.x;           // 32 tiles of 32 queries
    const int bh = blockIdx.y;           // b*8+h
    const int b = bh >> 3, h = bh & 7;
    const int tid = threadIdx.x;
    const int w = tid >> 6, l = tid & 63;
    const int qlo = qt * 32;
    const int len = xlen[b] >> 2;

    int s0 = qlo - 128; if (s0 < 0) s0 = 0;
    const int jmax = qlo + 51;
    int k0t[3]; int nt = 0;
#pragma unroll
    for (int t = 0; t < 3; ++t) {
        int k0 = s0 + t * 64;
        if (k0 <= jmax && k0 < len) { k0t[nt] = k0; ++nt; }
    }

    const bf16* qbase = qkv + (size_t)(b * S_LEN) * 3072 + h * DHEAD;
    const bf16* kbase = qbase + DMODEL;

    short8 qa[4];
    {
        const bf16* qr = qbase + (size_t)(qlo + w * 16 + (l & 15)) * 3072 + (l >> 4) * 8;
#pragma unroll
        for (int kk = 0; kk < 4; ++kk)
            qa[kk] = *(const short8*)(qr + kk * 32);
    }

    auto stageK = [&](int k0, int buf) {
#pragma unroll
        for (int c = 0; c < 8; ++c) {
            int rl = w * 32 + c * 4 + (l >> 4);
            int sr = k0 + rl; if (sr > S_LEN - 1) sr = S_LEN - 1;
            int sc = ((l & 15) * 8) ^ ((rl & 7) << 3);
            gl_lds16(kbase + (size_t)sr * 3072 + sc,
                     &KV[buf][(w * 32 + c * 4) * 128]);
        }
    };
    auto stageV = [&](int k0, int buf) {
#pragma unroll
        for (int c = 0; c < 8; ++c) {
            int d = w * 64 + c * 8 + (l >> 3);
            int js = ((l & 7) * 8) ^ ((d & 7) << 3);
            int s = k0 + js; if (s > S_LEN - 8) s = S_LEN - 8;
            gl_lds16(vt_g + (size_t)(bh * 128 + d) * 1024 + s,
                     &KV[buf][(w * 64 + c * 8) * 64]);
        }
    };

    f32x4 sf[3][4] = {};

    auto sphase = [&](int t, int buf) {
#pragma unroll
        for (int jb = 0; jb < 4; ++jb) {
            int row = jb * 16 + (l & 15);
#pragma unroll
            for (int kk = 0; kk < 4; ++kk) {
                int kel = (kk * 32 + (l >> 4) * 8) ^ ((row & 7) << 3);
                short8 kf = *(const short8*)(&KV[buf][row * 128 + kel]);
                sf[t][jb] = __builtin_amdgcn_mfma_f32_16x16x32_bf16(
                    qa[kk], kf, sf[t][jb], 0, 0, 0);
            }
        }
    };

    if (nt > 0) stageK(k0t[0], 0);
    __syncthreads();
    if (nt > 1) stageK(k0t[1], 1);
    if (nt > 0) sphase(0, 0);
    __syncthreads();
    if (nt > 2) stageK(k0t[2], 0);
    if (nt > 1) sphase(1, 1);
    __syncthreads();
    if (nt > 2) sphase(2, 0);
    if (nt > 0) stageV(k0t[0], 1);

    const float scale = 0.088388347648318447f;  // 1/sqrt(128)
    float mr[4] = {-1e30f, -1e30f, -1e30f, -1e30f};
#pragma unroll
    for (int t = 0; t < 3; ++t) if (t < nt) {
#pragma unroll
        for (int jb = 0; jb < 4; ++jb) {
            int j = k0t[t] + jb * 16 + (l & 15);
            bool jok = (j < len);
#pragma unroll
            for (int r = 0; r < 4; ++r) {
                int i = qlo + w * 16 + ((l >> 4) << 2) + r;
                float v = sf[t][jb][r] * scale;
                bool ok = jok && (j - i <= LFWD) && (i - j < WIN);
                v = ok ? v : -1e30f;
                sf[t][jb][r] = v;
                mr[r] = fmaxf(mr[r], v);
            }
        }
    }
#pragma unroll
    for (int o = 1; o <= 8; o <<= 1)
#pragma unroll
        for (int r = 0; r < 4; ++r)
            mr[r] = fmaxf(mr[r], __shfl_xor(mr[r], o, 64));

    float lr[4] = {0.0f, 0.0f, 0.0f, 0.0f};
#pragma unroll
    for (int t = 0; t < 3; ++t) if (t < nt) {
#pragma unroll
        for (int jb = 0; jb < 4; ++jb) {
#pragma unroll
            for (int r = 0; r < 4; ++r) {
                int q = ((l >> 4) << 2) + r;
                int jrel = t * 64 + jb * 16 + (l & 15);
                float e = __expf(sf[t][jb][r] - mr[r]);
                lr[r] += e;
                P[w][q * 192 + (jrel ^ ((q & 7) << 3))] = (bf16)e;
            }
        }
    }
#pragma unroll
    for (int o = 1; o <= 8; o <<= 1)
#pragma unroll
        for (int r = 0; r < 4; ++r)
            lr[r] += __shfl_xor(lr[r], o, 64);
    float inv[4];
#pragma unroll
    for (int r = 0; r < 4; ++r) inv[r] = 1.0f / fmaxf(lr[r], 1e-30f);

    __syncthreads();

    f32x4 acc[8] = {};
    auto pv = [&](int ti, int buf) {
#pragma unroll
        for (int s32 = 0; s32 < 2; ++s32) {
            int q = l & 15;
            int jr8 = ti * 64 + s32 * 32 + (l >> 4) * 8;
            short8 pa = *(const short8*)(&P[w][q * 192 + (jr8 ^ ((q & 7) << 3))]);
#pragma unroll
            for (int db = 0; db < 8; ++db) {
                int d = db * 16 + (l & 15);
                int je = (s32 * 32 + (l >> 4) * 8) ^ ((d & 7) << 3);
                short8 vf = *(const short8*)(&KV[buf][d * 64 + je]);
                acc[db] = __builtin_amdgcn_mfma_f32_16x16x32_bf16(
                    pa, vf, acc[db], 0, 0, 0);
            }
        }
    };

    if (nt > 1) stageV(k0t[1], 0);
    if (nt > 0) pv(0, 1);
    __syncthreads();
    if (nt > 2) stageV(k0t[2], 1);
    if (nt > 1) pv(1, 0);
    __syncthreads();
    if (nt > 2) pv(2, 1);

    const float* vm = vmean + (size_t)bh * DHEAD;
    float vmr[8];
#pragma unroll
    for (int db = 0; db < 8; ++db) vmr[db] = vm[db * 16 + (l & 15)];
#pragma unroll
    for (int r = 0; r < 4; ++r) {
        int i = qlo + w * 16 + ((l >> 4) << 2) + r;
        bf16* crow = ctx + (size_t)(b * S_LEN + i) * DMODEL + h * DHEAD;
        bool em = mr[r] < -1e29f;
        float iv = inv[r];
#pragma unroll
        for (int db = 0; db < 8; ++db) {
            float v = em ? vmr[db] : acc[db][r] * iv;
            crow[db * 16 + (l & 15)] = (bf16)v;
        }
    }
}

extern "C" void kernel_launch(void* const* d_in, const int* in_sizes, int n_in,
                              void* d_out, int out_size, void* d_ws, size_t ws_size,
                              hipStream_t stream)
{
    const float* x      = (const float*)d_in[0];
    const int*   xlen   = (const int*)d_in[1];
    const float* Wp     = (const float*)d_in[2];
    const float* bp     = (const float*)d_in[3];
    const float* ln1_s  = (const float*)d_in[4];
    const float* ln1_b  = (const float*)d_in[5];
    const float* Wq     = (const float*)d_in[6];
    const float* bq     = (const float*)d_in[7];
    const float* Wk     = (const float*)d_in[8];
    const float* bk     = (const float*)d_in[9];
    const float* Wv     = (const float*)d_in[10];
    const float* bv     = (const float*)d_in[11];
    const float* Wo     = (const float*)d_in[12];
    const float* bo     = (const float*)d_in[13];
    const float* ln2_s  = (const float*)d_in[14];
    const float* ln2_b  = (const float*)d_in[15];
    const float* W1     = (const float*)d_in[16];
    const float* b1     = (const float*)d_in[17];
    const float* W2     = (const float*)d_in[18];
    const float* b2     = (const float*)d_in[19];
    const float* lnf_s  = (const float*)d_in[20];
    const float* lnf_b  = (const float*)d_in[21];
    (void)in_sizes; (void)n_in; (void)out_size; (void)ws_size;

    const size_t MD = (size_t)M_ROWS * DMODEL;
    float* h     = (float*)d_ws;                          // [0,16) MB
    bf16*  y     = (bf16*)(h + MD);                       // [16,24) MB
    bf16*  U     = y + MD;                                // [24,56) MB union
    bf16*  xb    = U;
    bf16*  qkv   = U;
    bf16*  mid   = U;
    float* vmean = (float*)(U + 16 * 1024 * 1024);
    float* bqkv  = vmean + BATCH * NHEAD * DHEAD;
    bf16*  wt    = (bf16*)d_out;                          // [0,8) MB of d_out
    float* doP   = (float*)((char*)d_out + 8 * 1024 * 1024);
    float* vpart = doP;                                   // vmean partials
    bf16*  vt_g  = (bf16*)d_out;                          // V^T, 8 MB (wt dead)
    const int QS = 3 * DMODEL;

    dim3 blk(256);
    dim3 gAT(DMODEL / 128, M_ROWS / 128, 4);              // atomic split-K grid, 1024

    // xb = bf16(x); h = 0; h += xb @ Wp^T + bp (atomic sk4); zero padded rows
    cvt_kernel<<<(2 * MD) / (256 * 4), blk, 0, stream>>>(x, xb);
    transpose_kernel<<<dim3(DMODEL / 32, 2048 / 32), blk, 0, stream>>>(Wp, wt, 2048, DMODEL, DMODEL);
    zero_kernel<<<MD / (256 * 4), blk, 0, stream>>>(h);
    mfma_gemm_at<<<gAT, blk, 0, stream>>>(xb, wt, bp, h, M_ROWS, DMODEL, 2048);
    pad_zero_kernel<<<M_ROWS, blk, 0, stream>>>(h, xlen);

    for (int l = 0; l < 4; ++l) {
        const size_t wD  = (size_t)l * DMODEL * DMODEL;
        const size_t wF  = (size_t)l * DMODEL * DFF;
        const size_t wF2 = (size_t)l * DFF * DMODEL;
        const size_t vD  = (size_t)l * DMODEL;
        const size_t vF  = (size_t)l * DFF;

        ln_kernel<bf16><<<M_ROWS, blk, 0, stream>>>(h, ln1_s + vD, ln1_b + vD, y);

        transpose_kernel<<<dim3(32, 32), blk, 0, stream>>>(Wq + wD, wt, DMODEL, DMODEL, DMODEL);
        transpose_kernel<<<dim3(32, 32), blk, 0, stream>>>(Wk + wD, wt + MD / 4, DMODEL, DMODEL, DMODEL);
        transpose_kernel<<<dim3(32, 32), blk, 0, stream>>>(Wv + wD, wt + MD / 2, DMODEL, DMODEL, DMODEL);
        concat3_kernel<<<12, blk, 0, stream>>>(bq + vD, bk + vD, bv + vD, bqkv);
        mfma_gemm<bf16><<<dim3(3 * DMODEL / 128, M_ROWS / 128), blk, 0, stream>>>(
            y, wt, bqkv, qkv, M_ROWS, 3 * DMODEL, DMODEL, 0);

        bf16* qb = qkv;
        bf16* kb = qkv + DMODEL;
        bf16* vb = qkv + 2 * DMODEL;
        rope_kernel<<<(M_ROWS * NHEAD * 64) / 256, blk, 0, stream>>>(qb, kb, QS);
        vtrans_kernel<<<dim3(32, 4, 32), blk, 0, stream>>>(qkv, vt_g);
        vmean_part<<<BATCH * NHEAD * 32, dim3(DHEAD), 0, stream>>>(vb, vpart, QS);
        vmean_fin<<<BATCH * NHEAD, dim3(DHEAD), 0, stream>>>(vpart, vmean);
        attn_mfma<<<dim3(32, 32), dim3(128), 0, stream>>>(qkv, vt_g, vmean, xlen, y);

        // h += ctx @ Wo^T + bo  (atomic sk4; h already holds residual)
        transpose_kernel<<<dim3(32, 32), blk, 0, stream>>>(Wo + wD, wt, DMODEL, DMODEL, DMODEL);
        mfma_gemm_at<<<gAT, blk, 0, stream>>>(y, wt, bo + vD, h, M_ROWS, DMODEL, DMODEL);

        ln_kernel<bf16><<<M_ROWS, blk, 0, stream>>>(h, ln2_s + vD, ln2_b + vD, y);

        // FFN1 full width: mid = silu(y @ W1^T + b1)
        transpose_kernel<<<dim3(DFF / 32, DMODEL / 32), blk, 0, stream>>>(
            W1 + wF, wt, DMODEL, DFF, DFF);
        mfma_gemm<bf16><<<dim3(DFF / 128, M_ROWS / 128), blk, 0, stream>>>(
            y, wt, b1 + vF, mid, M_ROWS, DFF, DMODEL, 1);

        // FFN2: h += mid @ W2^T + b2  (atomic sk4)
        transpose_kernel<<<dim3(DMODEL / 32, DFF / 32), blk, 0, stream>>>(
            W2 + wF2, wt, DFF, DMODEL, DMODEL);
        mfma_gemm_at<<<gAT, blk, 0, stream>>>(mid, wt, b2 + vD, h, M_ROWS, DMODEL, DFF);
    }

    ln_kernel<float><<<M_ROWS, blk, 0, stream>>>(h, lnf_s, lnf_b, (float*)d_out);
}